// Round 12
// baseline (382.421 us; speedup 1.0000x reference)
//
#include <hip/hip_runtime.h>

typedef __bf16 bf16;
typedef __bf16 bf16x4 __attribute__((ext_vector_type(4)));
typedef __bf16 bf16x8 __attribute__((ext_vector_type(8)));
typedef float f32x4 __attribute__((ext_vector_type(4)));
typedef float f32x16 __attribute__((ext_vector_type(16)));

#define NB 2
#define SEQ 4096
#define HID 768
#define NHEAD 12
#define HDIM 64
#define MTOT (NB * SEQ)   // 8192
#define LOG2E 1.4426950408889634f

// ============ fragment-pack kernels ============
__device__ inline void pack_body(const float* __restrict__ in, bf16* __restrict__ out, int rt) {
    __shared__ alignas(16) bf16 T[16 * 264];
    const int lane = threadIdx.x;
    const int c = lane & 15, g = lane >> 4;
    const float4* in4 = (const float4*)in + (size_t)rt * 16 * (HID / 4);
    for (int chunk = 0; chunk < 3; chunk++) {
#pragma unroll
        for (int i = 0; i < 16; i++) {
            float4 v = in4[(size_t)i * (HID / 4) + chunk * 64 + lane];
            bf16x4 o;
            o[0] = (bf16)v.x; o[1] = (bf16)v.y; o[2] = (bf16)v.z; o[3] = (bf16)v.w;
            *(bf16x4*)&T[i * 264 + lane * 4] = o;
        }
        __syncthreads();
#pragma unroll
        for (int s = 0; s < 8; s++) {
            bf16x8 val = *(const bf16x8*)&T[c * 264 + s * 32 + g * 8];
            *(bf16x8*)(out + (((size_t)rt * 24 + chunk * 8 + s) * 64 + lane) * 8) = val;
        }
        __syncthreads();
    }
}

__global__ __launch_bounds__(64) void pack_a(const float* __restrict__ in, bf16* __restrict__ out) {
    pack_body(in, out, blockIdx.x);
}

__global__ __launch_bounds__(64) void pack_w4(
    const float* __restrict__ w0, const float* __restrict__ w1,
    const float* __restrict__ w2, const float* __restrict__ w3,
    bf16* __restrict__ o0, bf16* __restrict__ o1, bf16* __restrict__ o2, bf16* __restrict__ o3) {
    int y = blockIdx.y;
    const float* in = (y == 0) ? w0 : (y == 1) ? w1 : (y == 2) ? w2 : w3;
    bf16* out = (y == 0) ? o0 : (y == 1) ? o1 : (y == 2) ? o2 : o3;
    pack_body(in, out, blockIdx.x);
}

// mask weights: wexp[b][s] = exp2(mask*log2e) as f32 (for V scaling) and bf16 (for l-MFMA A-frag)
__global__ __launch_bounds__(256) void prep_mask(const float* __restrict__ mask,
                                                 float* __restrict__ wexp,
                                                 bf16* __restrict__ wp) {
    int idx = blockIdx.x * 256 + threadIdx.x;     // 0..8191
    float w = exp2f(mask[idx] * LOG2E);
    wexp[idx] = w;
    wp[idx] = (bf16)w;
}

// ============ fused QKV projection GEMM (packed operands, ping-pong K-loop) ============
// V rows are pre-scaled by the mask weight w[b][s] (masking folded out of attention loop).
__global__ __launch_bounds__(256, 3) void qkv_gemm(
    const bf16* __restrict__ Xp,
    const bf16* __restrict__ Wq, const bf16* __restrict__ Wk, const bf16* __restrict__ Wv,
    const float* __restrict__ bq, const float* __restrict__ bk, const float* __restrict__ bv,
    const float* __restrict__ wexp,
    bf16* __restrict__ Qh, bf16* __restrict__ Kh, bf16* __restrict__ Vt)
{
    int z = blockIdx.z;
    const bf16* W = (z == 0) ? Wq : (z == 1) ? Wk : Wv;
    const float* bias = (z == 0) ? bq : (z == 1) ? bk : bv;

    int lane = threadIdx.x & 63;
    int wid  = threadIdx.x >> 6;
    int wm = wid >> 1, wn = wid & 1;
    int g = lane >> 4, c = lane & 15;
    int m0 = blockIdx.y * 128 + wm * 64;
    int n0 = blockIdx.x * 128 + wn * 64;

    f32x4 acc[4][4] = {};
    const bf16* Ap = Xp + ((size_t)(m0 >> 4) * 24) * 512 + (size_t)lane * 8;
    const bf16* Bp = W  + ((size_t)(n0 >> 4) * 24) * 512 + (size_t)lane * 8;

    bf16x8 a0[4], b0[4];
#pragma unroll
    for (int i = 0; i < 4; i++) {
        a0[i] = *(const bf16x8*)(Ap + ((size_t)i * 24) * 512);
        b0[i] = *(const bf16x8*)(Bp + ((size_t)i * 24) * 512);
    }

    for (int ks = 0; ks < 24; ks += 2) {
        bf16x8 a1[4], b1[4];
#pragma unroll
        for (int i = 0; i < 4; i++) {              // prefetch odd step
            a1[i] = *(const bf16x8*)(Ap + ((size_t)i * 24 + ks + 1) * 512);
            b1[i] = *(const bf16x8*)(Bp + ((size_t)i * 24 + ks + 1) * 512);
        }
#pragma unroll
        for (int mi = 0; mi < 4; mi++)
#pragma unroll
            for (int ni = 0; ni < 4; ni++)
                acc[mi][ni] = __builtin_amdgcn_mfma_f32_16x16x32_bf16(a0[mi], b0[ni], acc[mi][ni], 0, 0, 0);
        int kn = (ks + 2 < 24) ? ks + 2 : 0;       // wrap: benign dummy on last iter
#pragma unroll
        for (int i = 0; i < 4; i++) {              // prefetch next even step
            a0[i] = *(const bf16x8*)(Ap + ((size_t)i * 24 + kn) * 512);
            b0[i] = *(const bf16x8*)(Bp + ((size_t)i * 24 + kn) * 512);
        }
#pragma unroll
        for (int mi = 0; mi < 4; mi++)
#pragma unroll
            for (int ni = 0; ni < 4; ni++)
                acc[mi][ni] = __builtin_amdgcn_mfma_f32_16x16x32_bf16(a1[mi], b1[ni], acc[mi][ni], 0, 0, 0);
    }

#pragma unroll
    for (int ni = 0; ni < 4; ni++) {
        int n = n0 + ni * 16 + c;
        float bval = bias[n];
        int h = n >> 6, d = n & 63;
#pragma unroll
        for (int mi = 0; mi < 4; mi++) {
#pragma unroll
            for (int j = 0; j < 4; j++) {
                int m = m0 + mi * 16 + g * 4 + j;
                float val = acc[mi][ni][j] + bval;
                int bb = m >> 12, s = m & 4095;
                size_t bhb = (size_t)(bb * NHEAD + h) * SEQ * HDIM;
                if (z == 0) {
                    val *= 0.125f * LOG2E;
                    Qh[bhb + (size_t)s * HDIM + d] = (bf16)val;
                } else if (z == 1) {
                    int fragidx = (((s >> 5) & 1) << 2) | (d >> 4);
                    int lane2 = (s & 31) | (((d >> 3) & 1) << 5);
                    Kh[bhb + (size_t)(s >> 6) * 4096 + fragidx * 512 + lane2 * 8 + (d & 7)] = (bf16)val;
                } else {
                    val *= wexp[bb * SEQ + s];      // fold mask weight into V rows
                    int fragidx = ((d >> 5) << 2) | ((s >> 4) & 3);
                    int lane2 = (d & 31) | (((s >> 3) & 1) << 5);
                    Vt[bhb + (size_t)(s >> 6) * 4096 + fragidx * 512 + lane2 * 8 + (s & 7)] = (bf16)val;
                }
            }
        }
    }
}

// ============ softmax helpers ============
__device__ inline float xhalf_max(float x) {
    float a_ = x, b_ = x;
    asm("v_permlane32_swap_b32 %0, %1" : "+v"(a_), "+v"(b_));
    return fmaxf(a_, b_);
}

// online softmax for one 32k x 32q block (unmasked scores; only max + exp here)
__device__ inline void smax16(f32x16& s, float& m, f32x16& o0, f32x16& o1, f32x16& la) {
    float t0 = fmaxf(fmaxf(s[0], s[1]), s[2]);      // -> v_max3
    float t1 = fmaxf(fmaxf(s[3], s[4]), s[5]);
    float t2 = fmaxf(fmaxf(s[6], s[7]), s[8]);
    float t3 = fmaxf(fmaxf(s[9], s[10]), s[11]);
    float t4 = fmaxf(fmaxf(s[12], s[13]), s[14]);
    float u0 = fmaxf(fmaxf(t0, t1), t2);
    float u1 = fmaxf(fmaxf(t3, t4), s[15]);
    float t = xhalf_max(fmaxf(u0, u1));
    if (__any(t > m + 8.f)) {          // defer-max (T13)
        float mn = fmaxf(m, t);
        float al = __builtin_amdgcn_exp2f(m - mn);
        m = mn;
#pragma unroll
        for (int i = 0; i < 16; i++) { o0[i] *= al; o1[i] *= al; la[i] *= al; }
    }
#pragma unroll
    for (int i = 0; i < 16; i++) s[i] = __builtin_amdgcn_exp2f(s[i] - m);
}

// P (f32 D-layout, one 32k block) -> 2 bf16 B-frags (k 0..15, 16..31)
__device__ inline void pconv16(const f32x16& sc, bf16x8* pa) {
    unsigned u[8];
#pragma unroll
    for (int i = 0; i < 8; i++) {
        union { bf16 hh[2]; unsigned uu; } x;
        x.hh[0] = (bf16)sc[i * 2];
        x.hh[1] = (bf16)sc[i * 2 + 1];
        u[i] = x.uu;
    }
    asm("v_permlane32_swap_b32 %0, %1" : "+v"(u[0]), "+v"(u[2]));
    asm("v_permlane32_swap_b32 %0, %1" : "+v"(u[1]), "+v"(u[3]));
    asm("v_permlane32_swap_b32 %0, %1" : "+v"(u[4]), "+v"(u[6]));
    asm("v_permlane32_swap_b32 %0, %1" : "+v"(u[5]), "+v"(u[7]));
    union { unsigned uu[4]; bf16x8 v; } f0, f1;
    f0.uu[0] = u[0]; f0.uu[1] = u[1]; f0.uu[2] = u[2]; f0.uu[3] = u[3];
    f1.uu[0] = u[4]; f1.uu[1] = u[5]; f1.uu[2] = u[6]; f1.uu[3] = u[7];
    pa[0] = f0.v;
    pa[1] = f1.v;
}

// ============ flash attention: mask-free loop, K ping-pong prefetch ============
// 4 waves = 2 q-groups x split-K-2, 32q/wave, 32k tiles. l via w-row MFMA; V pre-scaled by w.
// NOTE: 4-wave blocks co-schedule the two q-groups reading IDENTICAL K/V fragments ->
// intra-block L1/L2 locality. Splitting to 2-wave blocks doubled HBM fetch (R10 regression).
// launch_bounds(256,4): total regs = 76 VGPR + 48 AGPR = 124 <= 128 -> 4 waves/SIMD.
__global__ __launch_bounds__(256, 4) void attn_kernel(
    const bf16* __restrict__ Qh, const bf16* __restrict__ Kh, const bf16* __restrict__ Vt,
    const bf16* __restrict__ wp, bf16* __restrict__ ctxp)
{
    __shared__ float Sm[2][2048];              // 16KB: kp1 o-state per q-group
    __shared__ float Sml[2][128];              // 1KB:  kp1 m/l
    __shared__ alignas(16) bf16 Ep[2][2048];   // 8KB:  epilogue coalesce

    const int lane = threadIdx.x & 63;
    const int wid = threadIdx.x >> 6;
    const int qg = wid >> 1;                   // q-group 0/1
    const int kp = wid & 1;                    // k parity
    const int lq = lane & 31;
    const int hi = lane >> 5;
    const int bh = blockIdx.x;
    const int b = bh / NHEAD, h = bh % NHEAD;
    const size_t base = (size_t)bh * SEQ * HDIM;
    const int qw = blockIdx.y * 64 + qg * 32;  // this wave's 32 q-rows

    bf16x8 qf[4];
#pragma unroll
    for (int dc = 0; dc < 4; dc++)
        qf[dc] = *(const bf16x8*)(Qh + base + (size_t)(qw + lq) * HDIM + dc * 16 + hi * 8);

    const bf16* kfrag = Kh + base + (size_t)lane * 8;
    const bf16* vfrag = Vt + base + (size_t)lane * 8;
    const bf16* wrow = wp + b * SEQ + hi * 8;

    float m = -3e38f;
    f32x16 o0 = {}, o1 = {}, la = {};

    bf16x8 kfA[4], kfB[4];
    {
        const size_t tb0 = (size_t)(kp >> 1) * 4096;
        const int kh0 = kp & 1;
#pragma unroll
        for (int dc = 0; dc < 4; dc++)
            kfA[dc] = *(const bf16x8*)(kfrag + tb0 + (kh0 * 4 + dc) * 512);
    }

#define ITER(T, KFC, KFN)                                                                 \
    {                                                                                     \
        const int kt = 2 * (T) + kp;                                                      \
        const size_t tb = (size_t)(kt >> 1) * 4096;                                       \
        const int khalf = kt & 1;                                                         \
        f32x16 s = {};                                                                    \
        _Pragma("unroll")                                                                 \
        for (int dc = 0; dc < 4; dc++)                                                    \
            s = __builtin_amdgcn_mfma_f32_32x32x16_bf16(KFC[dc], qf[dc], s, 0, 0, 0);     \
        { /* prefetch next-iteration K (benign over-read on final iter) */                \
            const int kn = kt + 2;                                                        \
            const size_t tbn = (size_t)(kn >> 1) * 4096;                                  \
            const int khn = kn & 1;                                                       \
            _Pragma("unroll")                                                             \
            for (int dc = 0; dc < 4; dc++)                                                \
                KFN[dc] = *(const bf16x8*)(kfrag + tbn + (khn * 4 + dc) * 512);           \
        }                                                                                 \
        bf16x8 vf[4];                                                                     \
        vf[0] = *(const bf16x8*)(vfrag + tb + (khalf * 2 + 0) * 512);                     \
        vf[1] = *(const bf16x8*)(vfrag + tb + (khalf * 2 + 1) * 512);                     \
        vf[2] = *(const bf16x8*)(vfrag + tb + (4 + khalf * 2 + 0) * 512);                 \
        vf[3] = *(const bf16x8*)(vfrag + tb + (4 + khalf * 2 + 1) * 512);                 \
        bf16x8 wf0 = *(const bf16x8*)(wrow + kt * 32);                                    \
        bf16x8 wf1 = *(const bf16x8*)(wrow + kt * 32 + 16);                               \
        smax16(s, m, o0, o1, la);                                                         \
        bf16x8 pa[2];                                                                     \
        pconv16(s, pa);                                                                   \
        la = __builtin_amdgcn_mfma_f32_32x32x16_bf16(wf0, pa[0], la, 0, 0, 0);            \
        la = __builtin_amdgcn_mfma_f32_32x32x16_bf16(wf1, pa[1], la, 0, 0, 0);            \
        o0 = __builtin_amdgcn_mfma_f32_32x32x16_bf16(vf[0], pa[0], o0, 0, 0, 0);          \
        o0 = __builtin_amdgcn_mfma_f32_32x32x16_bf16(vf[1], pa[1], o0, 0, 0, 0);          \
        o1 = __builtin_amdgcn_mfma_f32_32x32x16_bf16(vf[2], pa[0], o1, 0, 0, 0);          \
        o1 = __builtin_amdgcn_mfma_f32_32x32x16_bf16(vf[3], pa[1], o1, 0, 0, 0);          \
    }

    for (int t = 0; t < SEQ / 64; t += 2) {
        ITER(t, kfA, kfB);
        ITER(t + 1, kfB, kfA);
    }
#undef ITER

    float l = la[0];

    // ---- split-K merge: kp1 parks state, kp0 combines ----
    if (kp == 1) {
#pragma unroll
        for (int i = 0; i < 16; i++) {
            Sm[qg][i * 64 + lane]        = o0[i];
            Sm[qg][(16 + i) * 64 + lane] = o1[i];
        }
        Sml[qg][lane] = m; Sml[qg][64 + lane] = l;
    }
    __syncthreads();
    if (kp == 1) return;

    {
        float mB = Sml[qg][lane], lB = Sml[qg][64 + lane];
        float mm = fmaxf(m, mB);
        float a = __builtin_amdgcn_exp2f(m - mm);
        float bb_ = __builtin_amdgcn_exp2f(mB - mm);
        l = l * a + lB * bb_;
#pragma unroll
        for (int i = 0; i < 16; i++) {
            o0[i] = o0[i] * a + Sm[qg][i * 64 + lane] * bb_;
            o1[i] = o1[i] * a + Sm[qg][(16 + i) * 64 + lane] * bb_;
        }
    }

    // ---- epilogue: O/l -> Ep (swizzled) -> ctx FRAG-PACKED for oproj ----
    float inv = 1.f / l;
    bf16* ep = Ep[qg];
    const int sw = (lq & 7) << 4;
#pragma unroll
    for (int g = 0; g < 4; g++) {
        bf16x4 p0, p1;
#pragma unroll
        for (int j = 0; j < 4; j++) {
            p0[j] = (bf16)(o0[g * 4 + j] * inv);
            p1[j] = (bf16)(o1[g * 4 + j] * inv);
        }
        int colb = g * 16 + hi * 8;
        *(bf16x4*)((char*)ep + lq * 128 + (colb ^ sw)) = p0;
        *(bf16x4*)((char*)ep + lq * 128 + ((64 + colb) ^ sw)) = p1;
    }
    const int c = lane & 15, gg = lane >> 4;
#pragma unroll
    for (int mt = 0; mt < 2; mt++) {
#pragma unroll
        for (int s2 = 0; s2 < 2; s2++) {
            int row = mt * 16 + c;
            int colb = (s2 * 64 + gg * 16) ^ ((row & 7) << 4);
            bf16x8 val = *(const bf16x8*)((const char*)ep + row * 128 + colb);
            size_t mtg = (size_t)((b * SEQ + qw) >> 4) + mt;
            *(bf16x8*)(ctxp + ((mtg * 24 + h * 2 + s2) * 64 + lane) * 8) = val;
        }
    }
}

// ============ output projection + bias + residual (packed operands, ping-pong K-loop) ============
__global__ __launch_bounds__(256, 3) void oproj_gemm(
    const bf16* __restrict__ Cp, const bf16* __restrict__ Wo, const float* __restrict__ bo,
    const float* __restrict__ hidden, float* __restrict__ y)
{
    int lane = threadIdx.x & 63;
    int wid  = threadIdx.x >> 6;
    int wm = wid >> 1, wn = wid & 1;
    int g = lane >> 4, c = lane & 15;
    int m0 = blockIdx.y * 128 + wm * 64;
    int n0 = blockIdx.x * 128 + wn * 64;

    f32x4 acc[4][4] = {};
    const bf16* Ap = Cp + ((size_t)(m0 >> 4) * 24) * 512 + (size_t)lane * 8;
    const bf16* Bp = Wo + ((size_t)(n0 >> 4) * 24) * 512 + (size_t)lane * 8;

    bf16x8 a0[4], b0[4];
#pragma unroll
    for (int i = 0; i < 4; i++) {
        a0[i] = *(const bf16x8*)(Ap + ((size_t)i * 24) * 512);
        b0[i] = *(const bf16x8*)(Bp + ((size_t)i * 24) * 512);
    }

    for (int ks = 0; ks < 24; ks += 2) {
        bf16x8 a1[4], b1[4];
#pragma unroll
        for (int i = 0; i < 4; i++) {
            a1[i] = *(const bf16x8*)(Ap + ((size_t)i * 24 + ks + 1) * 512);
            b1[i] = *(const bf16x8*)(Bp + ((size_t)i * 24 + ks + 1) * 512);
        }
#pragma unroll
        for (int mi = 0; mi < 4; mi++)
#pragma unroll
            for (int ni = 0; ni < 4; ni++)
                acc[mi][ni] = __builtin_amdgcn_mfma_f32_16x16x32_bf16(a0[mi], b0[ni], acc[mi][ni], 0, 0, 0);
        int kn = (ks + 2 < 24) ? ks + 2 : 0;
#pragma unroll
        for (int i = 0; i < 4; i++) {
            a0[i] = *(const bf16x8*)(Ap + ((size_t)i * 24 + kn) * 512);
            b0[i] = *(const bf16x8*)(Bp + ((size_t)i * 24 + kn) * 512);
        }
#pragma unroll
        for (int mi = 0; mi < 4; mi++)
#pragma unroll
            for (int ni = 0; ni < 4; ni++)
                acc[mi][ni] = __builtin_amdgcn_mfma_f32_16x16x32_bf16(a1[mi], b1[ni], acc[mi][ni], 0, 0, 0);
    }

#pragma unroll
    for (int ni = 0; ni < 4; ni++) {
        int n = n0 + ni * 16 + c;
        float bval = bo[n];
#pragma unroll
        for (int mi = 0; mi < 4; mi++) {
#pragma unroll
            for (int j = 0; j < 4; j++) {
                int m = m0 + mi * 16 + g * 4 + j;
                size_t idx = (size_t)m * HID + n;
                y[idx] = acc[mi][ni][j] + bval + hidden[idx];
            }
        }
    }
}

// ============ LayerNorm ============
__global__ __launch_bounds__(256) void ln_kernel(
    const float* __restrict__ y, const float* __restrict__ gam,
    const float* __restrict__ bet, float* __restrict__ out)
{
    int row = blockIdx.x * 4 + (threadIdx.x >> 6);
    int lane = threadIdx.x & 63;
    const float* yr = y + (size_t)row * HID;

    float4 v[3];
#pragma unroll
    for (int i = 0; i < 3; i++)
        v[i] = reinterpret_cast<const float4*>(yr)[lane + i * 64];

    float s = 0.f;
#pragma unroll
    for (int i = 0; i < 3; i++) s += v[i].x + v[i].y + v[i].z + v[i].w;
#pragma unroll
    for (int msk = 1; msk < 64; msk <<= 1) s += __shfl_xor(s, msk, 64);
    float mean = s * (1.f / 768.f);

    float q = 0.f;
#pragma unroll
    for (int i = 0; i < 3; i++) {
        float dx = v[i].x - mean, dy = v[i].y - mean, dz = v[i].z - mean, dw = v[i].w - mean;
        q += dx * dx + dy * dy + dz * dz + dw * dw;
    }
#pragma unroll
    for (int msk = 1; msk < 64; msk <<= 1) q += __shfl_xor(q, msk, 64);
    float rstd = rsqrtf(q * (1.f / 768.f) + 1e-12f);

    float* outr = out + (size_t)row * HID;
#pragma unroll
    for (int i = 0; i < 3; i++) {
        float4 gg = reinterpret_cast<const float4*>(gam)[lane + i * 64];
        float4 bb = reinterpret_cast<const float4*>(bet)[lane + i * 64];
        float4 o;
        o.x = (v[i].x - mean) * rstd * gg.x + bb.x;
        o.y = (v[i].y - mean) * rstd * gg.y + bb.y;
        o.z = (v[i].z - mean) * rstd * gg.z + bb.z;
        o.w = (v[i].w - mean) * rstd * gg.w + bb.w;
        reinterpret_cast<float4*>(outr)[lane + i * 64] = o;
    }
}

extern "C" void kernel_launch(void* const* d_in, const int* in_sizes, int n_in,
                              void* d_out, int out_size, void* d_ws, size_t ws_size,
                              hipStream_t stream) {
    const float* hidden = (const float*)d_in[0];
    const float* mask   = (const float*)d_in[1];
    const float* q_w = (const float*)d_in[2];
    const float* q_b = (const float*)d_in[3];
    const float* k_w = (const float*)d_in[4];
    const float* k_b = (const float*)d_in[5];
    const float* v_w = (const float*)d_in[6];
    const float* v_b = (const float*)d_in[7];
    const float* o_w = (const float*)d_in[8];
    const float* o_b = (const float*)d_in[9];
    const float* ln_g = (const float*)d_in[10];
    const float* ln_b = (const float*)d_in[11];
    float* out = (float*)d_out;

    const size_t SZ_X = (size_t)MTOT * HID;
    const size_t SZ_W = (size_t)HID * HID;

    char* ws = (char*)d_ws;
    size_t XB_OFF = 0;
    size_t W_OFF  = XB_OFF + SZ_X * 2;
    size_t QH_OFF = W_OFF + 4 * SZ_W * 2;
    size_t KH_OFF = QH_OFF + SZ_X * 2;
    size_t VT_OFF = KH_OFF + SZ_X * 2;
    size_t WE_OFF = VT_OFF + SZ_X * 2;           // wexp f32 (32KB)
    size_t WP_OFF = WE_OFF + (size_t)MTOT * 4;   // wp bf16 (16KB)

    bf16* Xp  = (bf16*)(ws + XB_OFF);
    bf16* Wqp = (bf16*)(ws + W_OFF);
    bf16* Wkp = Wqp + SZ_W;
    bf16* Wvp = Wkp + SZ_W;
    bf16* Wop = Wvp + SZ_W;
    bf16* Qh  = (bf16*)(ws + QH_OFF);
    bf16* Kh  = (bf16*)(ws + KH_OFF);
    bf16* Vt  = (bf16*)(ws + VT_OFF);
    float* wexp = (float*)(ws + WE_OFF);
    bf16* wp  = (bf16*)(ws + WP_OFF);
    bf16* ctxp = (bf16*)(ws + XB_OFF);   // alias: Xp dead after qkv_gemm
    float* y  = (float*)(ws + QH_OFF);   // alias: Qh/Kh dead after attn

    pack_a<<<dim3(MTOT / 16), 64, 0, stream>>>(hidden, Xp);
    pack_w4<<<dim3(HID / 16, 4), 64, 0, stream>>>(q_w, k_w, v_w, o_w, Wqp, Wkp, Wvp, Wop);
    prep_mask<<<dim3(MTOT / 256), 256, 0, stream>>>(mask, wexp, wp);

    qkv_gemm<<<dim3(HID / 128, MTOT / 128, 3), 256, 0, stream>>>(
        Xp, Wqp, Wkp, Wvp, q_b, k_b, v_b, wexp, Qh, Kh, Vt);

    // R9 config + 4-wave/SIMD occupancy cap
    attn_kernel<<<dim3(NB * NHEAD, SEQ / 64), 256, 0, stream>>>(Qh, Kh, Vt, wp, ctxp);

    oproj_gemm<<<dim3(HID / 128, MTOT / 128), 256, 0, stream>>>(ctxp, Wop, o_b, hidden, y);

    ln_kernel<<<dim3(MTOT / 4), 256, 0, stream>>>(y, ln_g, ln_b, out);
}

// Round 13
// 348.915 us; speedup vs baseline: 1.0960x; 1.0960x over previous
//
#include <hip/hip_runtime.h>

typedef __bf16 bf16;
typedef __bf16 bf16x4 __attribute__((ext_vector_type(4)));
typedef __bf16 bf16x8 __attribute__((ext_vector_type(8)));
typedef float f32x4 __attribute__((ext_vector_type(4)));
typedef float f32x16 __attribute__((ext_vector_type(16)));

#define NB 2
#define SEQ 4096
#define HID 768
#define NHEAD 12
#define HDIM 64
#define MTOT (NB * SEQ)   // 8192
#define LOG2E 1.4426950408889634f

// ============ fragment-pack kernels ============
__device__ inline void pack_body(const float* __restrict__ in, bf16* __restrict__ out, int rt) {
    __shared__ alignas(16) bf16 T[16 * 264];
    const int lane = threadIdx.x;
    const int c = lane & 15, g = lane >> 4;
    const float4* in4 = (const float4*)in + (size_t)rt * 16 * (HID / 4);
    for (int chunk = 0; chunk < 3; chunk++) {
#pragma unroll
        for (int i = 0; i < 16; i++) {
            float4 v = in4[(size_t)i * (HID / 4) + chunk * 64 + lane];
            bf16x4 o;
            o[0] = (bf16)v.x; o[1] = (bf16)v.y; o[2] = (bf16)v.z; o[3] = (bf16)v.w;
            *(bf16x4*)&T[i * 264 + lane * 4] = o;
        }
        __syncthreads();
#pragma unroll
        for (int s = 0; s < 8; s++) {
            bf16x8 val = *(const bf16x8*)&T[c * 264 + s * 32 + g * 8];
            *(bf16x8*)(out + (((size_t)rt * 24 + chunk * 8 + s) * 64 + lane) * 8) = val;
        }
        __syncthreads();
    }
}

__global__ __launch_bounds__(64) void pack_a(const float* __restrict__ in, bf16* __restrict__ out) {
    pack_body(in, out, blockIdx.x);
}

__global__ __launch_bounds__(64) void pack_w4(
    const float* __restrict__ w0, const float* __restrict__ w1,
    const float* __restrict__ w2, const float* __restrict__ w3,
    bf16* __restrict__ o0, bf16* __restrict__ o1, bf16* __restrict__ o2, bf16* __restrict__ o3) {
    int y = blockIdx.y;
    const float* in = (y == 0) ? w0 : (y == 1) ? w1 : (y == 2) ? w2 : w3;
    bf16* out = (y == 0) ? o0 : (y == 1) ? o1 : (y == 2) ? o2 : o3;
    pack_body(in, out, blockIdx.x);
}

// mask weights: wexp[b][s] = exp2(mask*log2e) as f32 (for V scaling) and bf16 (for l-MFMA A-frag)
__global__ __launch_bounds__(256) void prep_mask(const float* __restrict__ mask,
                                                 float* __restrict__ wexp,
                                                 bf16* __restrict__ wp) {
    int idx = blockIdx.x * 256 + threadIdx.x;     // 0..8191
    float w = exp2f(mask[idx] * LOG2E);
    wexp[idx] = w;
    wp[idx] = (bf16)w;
}

// ============ fused QKV projection GEMM (packed operands, ping-pong K-loop) ============
// V rows are pre-scaled by the mask weight w[b][s] (masking folded out of attention loop).
__global__ __launch_bounds__(256, 3) void qkv_gemm(
    const bf16* __restrict__ Xp,
    const bf16* __restrict__ Wq, const bf16* __restrict__ Wk, const bf16* __restrict__ Wv,
    const float* __restrict__ bq, const float* __restrict__ bk, const float* __restrict__ bv,
    const float* __restrict__ wexp,
    bf16* __restrict__ Qh, bf16* __restrict__ Kh, bf16* __restrict__ Vt)
{
    int z = blockIdx.z;
    const bf16* W = (z == 0) ? Wq : (z == 1) ? Wk : Wv;
    const float* bias = (z == 0) ? bq : (z == 1) ? bk : bv;

    int lane = threadIdx.x & 63;
    int wid  = threadIdx.x >> 6;
    int wm = wid >> 1, wn = wid & 1;
    int g = lane >> 4, c = lane & 15;
    int m0 = blockIdx.y * 128 + wm * 64;
    int n0 = blockIdx.x * 128 + wn * 64;

    f32x4 acc[4][4] = {};
    const bf16* Ap = Xp + ((size_t)(m0 >> 4) * 24) * 512 + (size_t)lane * 8;
    const bf16* Bp = W  + ((size_t)(n0 >> 4) * 24) * 512 + (size_t)lane * 8;

    bf16x8 a0[4], b0[4];
#pragma unroll
    for (int i = 0; i < 4; i++) {
        a0[i] = *(const bf16x8*)(Ap + ((size_t)i * 24) * 512);
        b0[i] = *(const bf16x8*)(Bp + ((size_t)i * 24) * 512);
    }

    for (int ks = 0; ks < 24; ks += 2) {
        bf16x8 a1[4], b1[4];
#pragma unroll
        for (int i = 0; i < 4; i++) {              // prefetch odd step
            a1[i] = *(const bf16x8*)(Ap + ((size_t)i * 24 + ks + 1) * 512);
            b1[i] = *(const bf16x8*)(Bp + ((size_t)i * 24 + ks + 1) * 512);
        }
#pragma unroll
        for (int mi = 0; mi < 4; mi++)
#pragma unroll
            for (int ni = 0; ni < 4; ni++)
                acc[mi][ni] = __builtin_amdgcn_mfma_f32_16x16x32_bf16(a0[mi], b0[ni], acc[mi][ni], 0, 0, 0);
        int kn = (ks + 2 < 24) ? ks + 2 : 0;       // wrap: benign dummy on last iter
#pragma unroll
        for (int i = 0; i < 4; i++) {              // prefetch next even step
            a0[i] = *(const bf16x8*)(Ap + ((size_t)i * 24 + kn) * 512);
            b0[i] = *(const bf16x8*)(Bp + ((size_t)i * 24 + kn) * 512);
        }
#pragma unroll
        for (int mi = 0; mi < 4; mi++)
#pragma unroll
            for (int ni = 0; ni < 4; ni++)
                acc[mi][ni] = __builtin_amdgcn_mfma_f32_16x16x32_bf16(a1[mi], b1[ni], acc[mi][ni], 0, 0, 0);
    }

#pragma unroll
    for (int ni = 0; ni < 4; ni++) {
        int n = n0 + ni * 16 + c;
        float bval = bias[n];
        int h = n >> 6, d = n & 63;
#pragma unroll
        for (int mi = 0; mi < 4; mi++) {
#pragma unroll
            for (int j = 0; j < 4; j++) {
                int m = m0 + mi * 16 + g * 4 + j;
                float val = acc[mi][ni][j] + bval;
                int bb = m >> 12, s = m & 4095;
                size_t bhb = (size_t)(bb * NHEAD + h) * SEQ * HDIM;
                if (z == 0) {
                    val *= 0.125f * LOG2E;
                    Qh[bhb + (size_t)s * HDIM + d] = (bf16)val;
                } else if (z == 1) {
                    int fragidx = (((s >> 5) & 1) << 2) | (d >> 4);
                    int lane2 = (s & 31) | (((d >> 3) & 1) << 5);
                    Kh[bhb + (size_t)(s >> 6) * 4096 + fragidx * 512 + lane2 * 8 + (d & 7)] = (bf16)val;
                } else {
                    val *= wexp[bb * SEQ + s];      // fold mask weight into V rows
                    int fragidx = ((d >> 5) << 2) | ((s >> 4) & 3);
                    int lane2 = (d & 31) | (((s >> 3) & 1) << 5);
                    Vt[bhb + (size_t)(s >> 6) * 4096 + fragidx * 512 + lane2 * 8 + (s & 7)] = (bf16)val;
                }
            }
        }
    }
}

// ============ softmax helpers ============
__device__ inline float xhalf_max(float x) {
    float a_ = x, b_ = x;
    asm("v_permlane32_swap_b32 %0, %1" : "+v"(a_), "+v"(b_));
    return fmaxf(a_, b_);
}

// online softmax for one 32k x 32q block (unmasked scores; only max + exp here)
__device__ inline void smax16(f32x16& s, float& m, f32x16& o0, f32x16& o1, f32x16& la) {
    float t0 = fmaxf(fmaxf(s[0], s[1]), s[2]);      // -> v_max3
    float t1 = fmaxf(fmaxf(s[3], s[4]), s[5]);
    float t2 = fmaxf(fmaxf(s[6], s[7]), s[8]);
    float t3 = fmaxf(fmaxf(s[9], s[10]), s[11]);
    float t4 = fmaxf(fmaxf(s[12], s[13]), s[14]);
    float u0 = fmaxf(fmaxf(t0, t1), t2);
    float u1 = fmaxf(fmaxf(t3, t4), s[15]);
    float t = xhalf_max(fmaxf(u0, u1));
    if (__any(t > m + 8.f)) {          // defer-max (T13)
        float mn = fmaxf(m, t);
        float al = __builtin_amdgcn_exp2f(m - mn);
        m = mn;
#pragma unroll
        for (int i = 0; i < 16; i++) { o0[i] *= al; o1[i] *= al; la[i] *= al; }
    }
#pragma unroll
    for (int i = 0; i < 16; i++) s[i] = __builtin_amdgcn_exp2f(s[i] - m);
}

// P (f32 D-layout, one 32k block) -> 2 bf16 B-frags (k 0..15, 16..31)
__device__ inline void pconv16(const f32x16& sc, bf16x8* pa) {
    unsigned u[8];
#pragma unroll
    for (int i = 0; i < 8; i++) {
        union { bf16 hh[2]; unsigned uu; } x;
        x.hh[0] = (bf16)sc[i * 2];
        x.hh[1] = (bf16)sc[i * 2 + 1];
        u[i] = x.uu;
    }
    asm("v_permlane32_swap_b32 %0, %1" : "+v"(u[0]), "+v"(u[2]));
    asm("v_permlane32_swap_b32 %0, %1" : "+v"(u[1]), "+v"(u[3]));
    asm("v_permlane32_swap_b32 %0, %1" : "+v"(u[4]), "+v"(u[6]));
    asm("v_permlane32_swap_b32 %0, %1" : "+v"(u[5]), "+v"(u[7]));
    union { unsigned uu[4]; bf16x8 v; } f0, f1;
    f0.uu[0] = u[0]; f0.uu[1] = u[1]; f0.uu[2] = u[2]; f0.uu[3] = u[3];
    f1.uu[0] = u[4]; f1.uu[1] = u[5]; f1.uu[2] = u[6]; f1.uu[3] = u[7];
    pa[0] = f0.v;
    pa[1] = f1.v;
}

// ============ flash attention: mask-free loop, K+V+w ping-pong prefetch ============
// 4 waves = 2 q-groups x split-K-2, 32q/wave, 32k tiles. l via w-row MFMA; V pre-scaled by w.
// NOTE: 4-wave blocks co-schedule the two q-groups reading IDENTICAL K/V fragments ->
// intra-block L1/L2 locality (2-wave blocks doubled HBM fetch, R10).
// (256,4) cap spilled to scratch (R12: WRITE_SIZE 32MB) -> stay at (256,3).
// All loop operands (K,V,w) prefetched one iteration ahead: chain = MFMA+VALU only.
__global__ __launch_bounds__(256, 3) void attn_kernel(
    const bf16* __restrict__ Qh, const bf16* __restrict__ Kh, const bf16* __restrict__ Vt,
    const bf16* __restrict__ wp, bf16* __restrict__ ctxp)
{
    __shared__ float Sm[2][2048];              // 16KB: kp1 o-state per q-group
    __shared__ float Sml[2][128];              // 1KB:  kp1 m/l
    __shared__ alignas(16) bf16 Ep[2][2048];   // 8KB:  epilogue coalesce

    const int lane = threadIdx.x & 63;
    const int wid = threadIdx.x >> 6;
    const int qg = wid >> 1;                   // q-group 0/1
    const int kp = wid & 1;                    // k parity
    const int lq = lane & 31;
    const int hi = lane >> 5;
    const int bh = blockIdx.x;
    const int b = bh / NHEAD, h = bh % NHEAD;
    const size_t base = (size_t)bh * SEQ * HDIM;
    const int qw = blockIdx.y * 64 + qg * 32;  // this wave's 32 q-rows

    bf16x8 qf[4];
#pragma unroll
    for (int dc = 0; dc < 4; dc++)
        qf[dc] = *(const bf16x8*)(Qh + base + (size_t)(qw + lq) * HDIM + dc * 16 + hi * 8);

    const bf16* kfrag = Kh + base + (size_t)lane * 8;
    const bf16* vfrag = Vt + base + (size_t)lane * 8;
    const bf16* wrow = wp + b * SEQ + hi * 8;

    float m = -3e38f;
    f32x16 o0 = {}, o1 = {}, la = {};

    bf16x8 kfA[4], kfB[4], vfA[4], vfB[4], wfA[2], wfB[2];
    {   // preload tile kp
        const size_t tb0 = (size_t)(kp >> 1) * 4096;
        const int kh0 = kp & 1;
#pragma unroll
        for (int dc = 0; dc < 4; dc++)
            kfA[dc] = *(const bf16x8*)(kfrag + tb0 + (kh0 * 4 + dc) * 512);
        vfA[0] = *(const bf16x8*)(vfrag + tb0 + (kh0 * 2 + 0) * 512);
        vfA[1] = *(const bf16x8*)(vfrag + tb0 + (kh0 * 2 + 1) * 512);
        vfA[2] = *(const bf16x8*)(vfrag + tb0 + (4 + kh0 * 2 + 0) * 512);
        vfA[3] = *(const bf16x8*)(vfrag + tb0 + (4 + kh0 * 2 + 1) * 512);
        wfA[0] = *(const bf16x8*)(wrow + kp * 32);
        wfA[1] = *(const bf16x8*)(wrow + kp * 32 + 16);
    }

#define ITER(T, KFC, KFN, VFC, VFN, WFC, WFN)                                             \
    {                                                                                     \
        const int kt = 2 * (T) + kp;                                                      \
        f32x16 s = {};                                                                    \
        _Pragma("unroll")                                                                 \
        for (int dc = 0; dc < 4; dc++)                                                    \
            s = __builtin_amdgcn_mfma_f32_32x32x16_bf16(KFC[dc], qf[dc], s, 0, 0, 0);     \
        { /* prefetch next-iteration K,V,w (clamped on final iter) */                     \
            const int kn = (kt + 2 < 128) ? kt + 2 : kt;                                  \
            const size_t tbn = (size_t)(kn >> 1) * 4096;                                  \
            const int khn = kn & 1;                                                       \
            _Pragma("unroll")                                                             \
            for (int dc = 0; dc < 4; dc++)                                                \
                KFN[dc] = *(const bf16x8*)(kfrag + tbn + (khn * 4 + dc) * 512);           \
            VFN[0] = *(const bf16x8*)(vfrag + tbn + (khn * 2 + 0) * 512);                 \
            VFN[1] = *(const bf16x8*)(vfrag + tbn + (khn * 2 + 1) * 512);                 \
            VFN[2] = *(const bf16x8*)(vfrag + tbn + (4 + khn * 2 + 0) * 512);             \
            VFN[3] = *(const bf16x8*)(vfrag + tbn + (4 + khn * 2 + 1) * 512);             \
            WFN[0] = *(const bf16x8*)(wrow + kn * 32);                                    \
            WFN[1] = *(const bf16x8*)(wrow + kn * 32 + 16);                               \
        }                                                                                 \
        smax16(s, m, o0, o1, la);                                                         \
        bf16x8 pa[2];                                                                     \
        pconv16(s, pa);                                                                   \
        o0 = __builtin_amdgcn_mfma_f32_32x32x16_bf16(VFC[0], pa[0], o0, 0, 0, 0);         \
        o0 = __builtin_amdgcn_mfma_f32_32x32x16_bf16(VFC[1], pa[1], o0, 0, 0, 0);         \
        o1 = __builtin_amdgcn_mfma_f32_32x32x16_bf16(VFC[2], pa[0], o1, 0, 0, 0);         \
        o1 = __builtin_amdgcn_mfma_f32_32x32x16_bf16(VFC[3], pa[1], o1, 0, 0, 0);         \
        la = __builtin_amdgcn_mfma_f32_32x32x16_bf16(WFC[0], pa[0], la, 0, 0, 0);         \
        la = __builtin_amdgcn_mfma_f32_32x32x16_bf16(WFC[1], pa[1], la, 0, 0, 0);         \
    }

    for (int t = 0; t < SEQ / 64; t += 2) {
        ITER(t, kfA, kfB, vfA, vfB, wfA, wfB);
        ITER(t + 1, kfB, kfA, vfB, vfA, wfB, wfA);
    }
#undef ITER

    float l = la[0];

    // ---- split-K merge: kp1 parks state, kp0 combines ----
    if (kp == 1) {
#pragma unroll
        for (int i = 0; i < 16; i++) {
            Sm[qg][i * 64 + lane]        = o0[i];
            Sm[qg][(16 + i) * 64 + lane] = o1[i];
        }
        Sml[qg][lane] = m; Sml[qg][64 + lane] = l;
    }
    __syncthreads();
    if (kp == 1) return;

    {
        float mB = Sml[qg][lane], lB = Sml[qg][64 + lane];
        float mm = fmaxf(m, mB);
        float a = __builtin_amdgcn_exp2f(m - mm);
        float bb_ = __builtin_amdgcn_exp2f(mB - mm);
        l = l * a + lB * bb_;
#pragma unroll
        for (int i = 0; i < 16; i++) {
            o0[i] = o0[i] * a + Sm[qg][i * 64 + lane] * bb_;
            o1[i] = o1[i] * a + Sm[qg][(16 + i) * 64 + lane] * bb_;
        }
    }

    // ---- epilogue: O/l -> Ep (swizzled) -> ctx FRAG-PACKED for oproj ----
    float inv = 1.f / l;
    bf16* ep = Ep[qg];
    const int sw = (lq & 7) << 4;
#pragma unroll
    for (int g = 0; g < 4; g++) {
        bf16x4 p0, p1;
#pragma unroll
        for (int j = 0; j < 4; j++) {
            p0[j] = (bf16)(o0[g * 4 + j] * inv);
            p1[j] = (bf16)(o1[g * 4 + j] * inv);
        }
        int colb = g * 16 + hi * 8;
        *(bf16x4*)((char*)ep + lq * 128 + (colb ^ sw)) = p0;
        *(bf16x4*)((char*)ep + lq * 128 + ((64 + colb) ^ sw)) = p1;
    }
    const int c = lane & 15, gg = lane >> 4;
#pragma unroll
    for (int mt = 0; mt < 2; mt++) {
#pragma unroll
        for (int s2 = 0; s2 < 2; s2++) {
            int row = mt * 16 + c;
            int colb = (s2 * 64 + gg * 16) ^ ((row & 7) << 4);
            bf16x8 val = *(const bf16x8*)((const char*)ep + row * 128 + colb);
            size_t mtg = (size_t)((b * SEQ + qw) >> 4) + mt;
            *(bf16x8*)(ctxp + ((mtg * 24 + h * 2 + s2) * 64 + lane) * 8) = val;
        }
    }
}

// ============ output projection + bias + residual (packed operands, ping-pong K-loop) ============
__global__ __launch_bounds__(256, 3) void oproj_gemm(
    const bf16* __restrict__ Cp, const bf16* __restrict__ Wo, const float* __restrict__ bo,
    const float* __restrict__ hidden, float* __restrict__ y)
{
    int lane = threadIdx.x & 63;
    int wid  = threadIdx.x >> 6;
    int wm = wid >> 1, wn = wid & 1;
    int g = lane >> 4, c = lane & 15;
    int m0 = blockIdx.y * 128 + wm * 64;
    int n0 = blockIdx.x * 128 + wn * 64;

    f32x4 acc[4][4] = {};
    const bf16* Ap = Cp + ((size_t)(m0 >> 4) * 24) * 512 + (size_t)lane * 8;
    const bf16* Bp = Wo + ((size_t)(n0 >> 4) * 24) * 512 + (size_t)lane * 8;

    bf16x8 a0[4], b0[4];
#pragma unroll
    for (int i = 0; i < 4; i++) {
        a0[i] = *(const bf16x8*)(Ap + ((size_t)i * 24) * 512);
        b0[i] = *(const bf16x8*)(Bp + ((size_t)i * 24) * 512);
    }

    for (int ks = 0; ks < 24; ks += 2) {
        bf16x8 a1[4], b1[4];
#pragma unroll
        for (int i = 0; i < 4; i++) {
            a1[i] = *(const bf16x8*)(Ap + ((size_t)i * 24 + ks + 1) * 512);
            b1[i] = *(const bf16x8*)(Bp + ((size_t)i * 24 + ks + 1) * 512);
        }
#pragma unroll
        for (int mi = 0; mi < 4; mi++)
#pragma unroll
            for (int ni = 0; ni < 4; ni++)
                acc[mi][ni] = __builtin_amdgcn_mfma_f32_16x16x32_bf16(a0[mi], b0[ni], acc[mi][ni], 0, 0, 0);
        int kn = (ks + 2 < 24) ? ks + 2 : 0;
#pragma unroll
        for (int i = 0; i < 4; i++) {
            a0[i] = *(const bf16x8*)(Ap + ((size_t)i * 24 + kn) * 512);
            b0[i] = *(const bf16x8*)(Bp + ((size_t)i * 24 + kn) * 512);
        }
#pragma unroll
        for (int mi = 0; mi < 4; mi++)
#pragma unroll
            for (int ni = 0; ni < 4; ni++)
                acc[mi][ni] = __builtin_amdgcn_mfma_f32_16x16x32_bf16(a1[mi], b1[ni], acc[mi][ni], 0, 0, 0);
    }

#pragma unroll
    for (int ni = 0; ni < 4; ni++) {
        int n = n0 + ni * 16 + c;
        float bval = bo[n];
#pragma unroll
        for (int mi = 0; mi < 4; mi++) {
#pragma unroll
            for (int j = 0; j < 4; j++) {
                int m = m0 + mi * 16 + g * 4 + j;
                size_t idx = (size_t)m * HID + n;
                y[idx] = acc[mi][ni][j] + bval + hidden[idx];
            }
        }
    }
}

// ============ LayerNorm ============
__global__ __launch_bounds__(256) void ln_kernel(
    const float* __restrict__ y, const float* __restrict__ gam,
    const float* __restrict__ bet, float* __restrict__ out)
{
    int row = blockIdx.x * 4 + (threadIdx.x >> 6);
    int lane = threadIdx.x & 63;
    const float* yr = y + (size_t)row * HID;

    float4 v[3];
#pragma unroll
    for (int i = 0; i < 3; i++)
        v[i] = reinterpret_cast<const float4*>(yr)[lane + i * 64];

    float s = 0.f;
#pragma unroll
    for (int i = 0; i < 3; i++) s += v[i].x + v[i].y + v[i].z + v[i].w;
#pragma unroll
    for (int msk = 1; msk < 64; msk <<= 1) s += __shfl_xor(s, msk, 64);
    float mean = s * (1.f / 768.f);

    float q = 0.f;
#pragma unroll
    for (int i = 0; i < 3; i++) {
        float dx = v[i].x - mean, dy = v[i].y - mean, dz = v[i].z - mean, dw = v[i].w - mean;
        q += dx * dx + dy * dy + dz * dz + dw * dw;
    }
#pragma unroll
    for (int msk = 1; msk < 64; msk <<= 1) q += __shfl_xor(q, msk, 64);
    float rstd = rsqrtf(q * (1.f / 768.f) + 1e-12f);

    float* outr = out + (size_t)row * HID;
#pragma unroll
    for (int i = 0; i < 3; i++) {
        float4 gg = reinterpret_cast<const float4*>(gam)[lane + i * 64];
        float4 bb = reinterpret_cast<const float4*>(bet)[lane + i * 64];
        float4 o;
        o.x = (v[i].x - mean) * rstd * gg.x + bb.x;
        o.y = (v[i].y - mean) * rstd * gg.y + bb.y;
        o.z = (v[i].z - mean) * rstd * gg.z + bb.z;
        o.w = (v[i].w - mean) * rstd * gg.w + bb.w;
        reinterpret_cast<float4*>(outr)[lane + i * 64] = o;
    }
}

extern "C" void kernel_launch(void* const* d_in, const int* in_sizes, int n_in,
                              void* d_out, int out_size, void* d_ws, size_t ws_size,
                              hipStream_t stream) {
    const float* hidden = (const float*)d_in[0];
    const float* mask   = (const float*)d_in[1];
    const float* q_w = (const float*)d_in[2];
    const float* q_b = (const float*)d_in[3];
    const float* k_w = (const float*)d_in[4];
    const float* k_b = (const float*)d_in[5];
    const float* v_w = (const float*)d_in[6];
    const float* v_b = (const float*)d_in[7];
    const float* o_w = (const float*)d_in[8];
    const float* o_b = (const float*)d_in[9];
    const float* ln_g = (const float*)d_in[10];
    const float* ln_b = (const float*)d_in[11];
    float* out = (float*)d_out;

    const size_t SZ_X = (size_t)MTOT * HID;
    const size_t SZ_W = (size_t)HID * HID;

    char* ws = (char*)d_ws;
    size_t XB_OFF = 0;
    size_t W_OFF  = XB_OFF + SZ_X * 2;
    size_t QH_OFF = W_OFF + 4 * SZ_W * 2;
    size_t KH_OFF = QH_OFF + SZ_X * 2;
    size_t VT_OFF = KH_OFF + SZ_X * 2;
    size_t WE_OFF = VT_OFF + SZ_X * 2;           // wexp f32 (32KB)
    size_t WP_OFF = WE_OFF + (size_t)MTOT * 4;   // wp bf16 (16KB)

    bf16* Xp  = (bf16*)(ws + XB_OFF);
    bf16* Wqp = (bf16*)(ws + W_OFF);
    bf16* Wkp = Wqp + SZ_W;
    bf16* Wvp = Wkp + SZ_W;
    bf16* Wop = Wvp + SZ_W;
    bf16* Qh  = (bf16*)(ws + QH_OFF);
    bf16* Kh  = (bf16*)(ws + KH_OFF);
    bf16* Vt  = (bf16*)(ws + VT_OFF);
    float* wexp = (float*)(ws + WE_OFF);
    bf16* wp  = (bf16*)(ws + WP_OFF);
    bf16* ctxp = (bf16*)(ws + XB_OFF);   // alias: Xp dead after qkv_gemm
    float* y  = (float*)(ws + QH_OFF);   // alias: Qh/Kh dead after attn

    pack_a<<<dim3(MTOT / 16), 64, 0, stream>>>(hidden, Xp);
    pack_w4<<<dim3(HID / 16, 4), 64, 0, stream>>>(q_w, k_w, v_w, o_w, Wqp, Wkp, Wvp, Wop);
    prep_mask<<<dim3(MTOT / 256), 256, 0, stream>>>(mask, wexp, wp);

    qkv_gemm<<<dim3(HID / 128, MTOT / 128, 3), 256, 0, stream>>>(
        Xp, Wqp, Wkp, Wvp, q_b, k_b, v_b, wexp, Qh, Kh, Vt);

    // R9/R11 config (256,3) + full K/V/w ping-pong prefetch
    attn_kernel<<<dim3(NB * NHEAD, SEQ / 64), 256, 0, stream>>>(Qh, Kh, Vt, wp, ctxp);

    oproj_gemm<<<dim3(HID / 128, MTOT / 128), 256, 0, stream>>>(ctxp, Wop, o_b, hidden, y);

    ln_kernel<<<dim3(MTOT / 4), 256, 0, stream>>>(y, ln_g, ln_b, out);
}

// Round 14
// 263.447 us; speedup vs baseline: 1.4516x; 1.3244x over previous
//
#include <hip/hip_runtime.h>

typedef __bf16 bf16;
typedef __bf16 bf16x4 __attribute__((ext_vector_type(4)));
typedef __bf16 bf16x8 __attribute__((ext_vector_type(8)));
typedef float f32x4 __attribute__((ext_vector_type(4)));
typedef float f32x16 __attribute__((ext_vector_type(16)));

#define NB 2
#define SEQ 4096
#define HID 768
#define NHEAD 12
#define HDIM 64
#define MTOT (NB * SEQ)   // 8192
#define LOG2E 1.4426950408889634f

// ============ fragment-pack kernels ============
__device__ inline void pack_body(const float* __restrict__ in, bf16* __restrict__ out, int rt) {
    __shared__ alignas(16) bf16 T[16 * 264];
    const int lane = threadIdx.x;
    const int c = lane & 15, g = lane >> 4;
    const float4* in4 = (const float4*)in + (size_t)rt * 16 * (HID / 4);
    for (int chunk = 0; chunk < 3; chunk++) {
#pragma unroll
        for (int i = 0; i < 16; i++) {
            float4 v = in4[(size_t)i * (HID / 4) + chunk * 64 + lane];
            bf16x4 o;
            o[0] = (bf16)v.x; o[1] = (bf16)v.y; o[2] = (bf16)v.z; o[3] = (bf16)v.w;
            *(bf16x4*)&T[i * 264 + lane * 4] = o;
        }
        __syncthreads();
#pragma unroll
        for (int s = 0; s < 8; s++) {
            bf16x8 val = *(const bf16x8*)&T[c * 264 + s * 32 + g * 8];
            *(bf16x8*)(out + (((size_t)rt * 24 + chunk * 8 + s) * 64 + lane) * 8) = val;
        }
        __syncthreads();
    }
}

// X (512 row-tiles) + 4 weight matrices (48 row-tiles each) in one launch
__global__ __launch_bounds__(64) void pack_aw(
    const float* __restrict__ X,
    const float* __restrict__ w0, const float* __restrict__ w1,
    const float* __restrict__ w2, const float* __restrict__ w3,
    bf16* __restrict__ oX,
    bf16* __restrict__ o0, bf16* __restrict__ o1, bf16* __restrict__ o2, bf16* __restrict__ o3) {
    int bid = blockIdx.x;
    if (bid < 512) {
        pack_body(X, oX, bid);
    } else {
        int t = bid - 512;
        int y = t / 48, rt = t % 48;
        const float* in = (y == 0) ? w0 : (y == 1) ? w1 : (y == 2) ? w2 : w3;
        bf16* out = (y == 0) ? o0 : (y == 1) ? o1 : (y == 2) ? o2 : o3;
        pack_body(in, out, rt);
    }
}

// mask weights: wexp[b][s] = exp2(mask*log2e) as f32 (for V scaling) and bf16 (for l-MFMA A-frag)
__global__ __launch_bounds__(256) void prep_mask(const float* __restrict__ mask,
                                                 float* __restrict__ wexp,
                                                 bf16* __restrict__ wp) {
    int idx = blockIdx.x * 256 + threadIdx.x;     // 0..8191
    float w = exp2f(mask[idx] * LOG2E);
    wexp[idx] = w;
    wp[idx] = (bf16)w;
}

// ============ fused QKV projection GEMM (packed operands, ping-pong K-loop) ============
__global__ __launch_bounds__(256, 3) void qkv_gemm(
    const bf16* __restrict__ Xp,
    const bf16* __restrict__ Wq, const bf16* __restrict__ Wk, const bf16* __restrict__ Wv,
    const float* __restrict__ bq, const float* __restrict__ bk, const float* __restrict__ bv,
    const float* __restrict__ wexp,
    bf16* __restrict__ Qh, bf16* __restrict__ Kh, bf16* __restrict__ Vt)
{
    int z = blockIdx.z;
    const bf16* W = (z == 0) ? Wq : (z == 1) ? Wk : Wv;
    const float* bias = (z == 0) ? bq : (z == 1) ? bk : bv;

    int lane = threadIdx.x & 63;
    int wid  = threadIdx.x >> 6;
    int wm = wid >> 1, wn = wid & 1;
    int g = lane >> 4, c = lane & 15;
    int m0 = blockIdx.y * 128 + wm * 64;
    int n0 = blockIdx.x * 128 + wn * 64;

    f32x4 acc[4][4] = {};
    const bf16* Ap = Xp + ((size_t)(m0 >> 4) * 24) * 512 + (size_t)lane * 8;
    const bf16* Bp = W  + ((size_t)(n0 >> 4) * 24) * 512 + (size_t)lane * 8;

    bf16x8 a0[4], b0[4];
#pragma unroll
    for (int i = 0; i < 4; i++) {
        a0[i] = *(const bf16x8*)(Ap + ((size_t)i * 24) * 512);
        b0[i] = *(const bf16x8*)(Bp + ((size_t)i * 24) * 512);
    }

    for (int ks = 0; ks < 24; ks += 2) {
        bf16x8 a1[4], b1[4];
#pragma unroll
        for (int i = 0; i < 4; i++) {
            a1[i] = *(const bf16x8*)(Ap + ((size_t)i * 24 + ks + 1) * 512);
            b1[i] = *(const bf16x8*)(Bp + ((size_t)i * 24 + ks + 1) * 512);
        }
#pragma unroll
        for (int mi = 0; mi < 4; mi++)
#pragma unroll
            for (int ni = 0; ni < 4; ni++)
                acc[mi][ni] = __builtin_amdgcn_mfma_f32_16x16x32_bf16(a0[mi], b0[ni], acc[mi][ni], 0, 0, 0);
        int kn = (ks + 2 < 24) ? ks + 2 : 0;
#pragma unroll
        for (int i = 0; i < 4; i++) {
            a0[i] = *(const bf16x8*)(Ap + ((size_t)i * 24 + kn) * 512);
            b0[i] = *(const bf16x8*)(Bp + ((size_t)i * 24 + kn) * 512);
        }
#pragma unroll
        for (int mi = 0; mi < 4; mi++)
#pragma unroll
            for (int ni = 0; ni < 4; ni++)
                acc[mi][ni] = __builtin_amdgcn_mfma_f32_16x16x32_bf16(a1[mi], b1[ni], acc[mi][ni], 0, 0, 0);
    }

#pragma unroll
    for (int ni = 0; ni < 4; ni++) {
        int n = n0 + ni * 16 + c;
        float bval = bias[n];
        int h = n >> 6, d = n & 63;
#pragma unroll
        for (int mi = 0; mi < 4; mi++) {
#pragma unroll
            for (int j = 0; j < 4; j++) {
                int m = m0 + mi * 16 + g * 4 + j;
                float val = acc[mi][ni][j] + bval;
                int bb = m >> 12, s = m & 4095;
                size_t bhb = (size_t)(bb * NHEAD + h) * SEQ * HDIM;
                if (z == 0) {
                    val *= 0.125f * LOG2E;
                    Qh[bhb + (size_t)s * HDIM + d] = (bf16)val;
                } else if (z == 1) {
                    int fragidx = (((s >> 5) & 1) << 2) | (d >> 4);
                    int lane2 = (s & 31) | (((d >> 3) & 1) << 5);
                    Kh[bhb + (size_t)(s >> 6) * 4096 + fragidx * 512 + lane2 * 8 + (d & 7)] = (bf16)val;
                } else {
                    val *= wexp[bb * SEQ + s];      // fold mask weight into V rows
                    int fragidx = ((d >> 5) << 2) | ((s >> 4) & 3);
                    int lane2 = (d & 31) | (((s >> 3) & 1) << 5);
                    Vt[bhb + (size_t)(s >> 6) * 4096 + fragidx * 512 + lane2 * 8 + (s & 7)] = (bf16)val;
                }
            }
        }
    }
}

// ============ softmax helpers ============
__device__ inline float xhalf_max(float x) {
    float a_ = x, b_ = x;
    asm("v_permlane32_swap_b32 %0, %1" : "+v"(a_), "+v"(b_));
    return fmaxf(a_, b_);
}

__device__ inline void smax16(f32x16& s, float& m, f32x16& o0, f32x16& o1, f32x16& la) {
    float t0 = fmaxf(fmaxf(s[0], s[1]), s[2]);      // -> v_max3
    float t1 = fmaxf(fmaxf(s[3], s[4]), s[5]);
    float t2 = fmaxf(fmaxf(s[6], s[7]), s[8]);
    float t3 = fmaxf(fmaxf(s[9], s[10]), s[11]);
    float t4 = fmaxf(fmaxf(s[12], s[13]), s[14]);
    float u0 = fmaxf(fmaxf(t0, t1), t2);
    float u1 = fmaxf(fmaxf(t3, t4), s[15]);
    float t = xhalf_max(fmaxf(u0, u1));
    if (__any(t > m + 8.f)) {          // defer-max (T13)
        float mn = fmaxf(m, t);
        float al = __builtin_amdgcn_exp2f(m - mn);
        m = mn;
#pragma unroll
        for (int i = 0; i < 16; i++) { o0[i] *= al; o1[i] *= al; la[i] *= al; }
    }
#pragma unroll
    for (int i = 0; i < 16; i++) s[i] = __builtin_amdgcn_exp2f(s[i] - m);
}

__device__ inline void pconv16(const f32x16& sc, bf16x8* pa) {
    unsigned u[8];
#pragma unroll
    for (int i = 0; i < 8; i++) {
        union { bf16 hh[2]; unsigned uu; } x;
        x.hh[0] = (bf16)sc[i * 2];
        x.hh[1] = (bf16)sc[i * 2 + 1];
        u[i] = x.uu;
    }
    asm("v_permlane32_swap_b32 %0, %1" : "+v"(u[0]), "+v"(u[2]));
    asm("v_permlane32_swap_b32 %0, %1" : "+v"(u[1]), "+v"(u[3]));
    asm("v_permlane32_swap_b32 %0, %1" : "+v"(u[4]), "+v"(u[6]));
    asm("v_permlane32_swap_b32 %0, %1" : "+v"(u[5]), "+v"(u[7]));
    union { unsigned uu[4]; bf16x8 v; } f0, f1;
    f0.uu[0] = u[0]; f0.uu[1] = u[1]; f0.uu[2] = u[2]; f0.uu[3] = u[3];
    f1.uu[0] = u[4]; f1.uu[1] = u[5]; f1.uu[2] = u[6]; f1.uu[3] = u[7];
    pa[0] = f0.v;
    pa[1] = f1.v;
}

// ============ flash attention: R11 config (best measured: 160us, 76 VGPR, no spill) ============
// 4 waves = 2 q-groups x split-K-2, 32q/wave, 32k tiles. Mask-free (w folded into V + l-MFMA).
// K-only ping-pong: deeper prefetch (V,w too) spills at any cap (R12: 128-cap, R13: 170-cap).
// 4-wave blocks co-schedule q-groups on identical K/V -> L1/L2 locality (R10: 2-wave = 2x HBM).
__global__ __launch_bounds__(256, 3) void attn_kernel(
    const bf16* __restrict__ Qh, const bf16* __restrict__ Kh, const bf16* __restrict__ Vt,
    const bf16* __restrict__ wp, bf16* __restrict__ ctxp)
{
    __shared__ float Sm[2][2048];              // 16KB: kp1 o-state per q-group
    __shared__ float Sml[2][128];              // 1KB:  kp1 m/l
    __shared__ alignas(16) bf16 Ep[2][2048];   // 8KB:  epilogue coalesce

    const int lane = threadIdx.x & 63;
    const int wid = threadIdx.x >> 6;
    const int qg = wid >> 1;                   // q-group 0/1
    const int kp = wid & 1;                    // k parity
    const int lq = lane & 31;
    const int hi = lane >> 5;
    const int bh = blockIdx.x;
    const int b = bh / NHEAD, h = bh % NHEAD;
    const size_t base = (size_t)bh * SEQ * HDIM;
    const int qw = blockIdx.y * 64 + qg * 32;  // this wave's 32 q-rows

    bf16x8 qf[4];
#pragma unroll
    for (int dc = 0; dc < 4; dc++)
        qf[dc] = *(const bf16x8*)(Qh + base + (size_t)(qw + lq) * HDIM + dc * 16 + hi * 8);

    const bf16* kfrag = Kh + base + (size_t)lane * 8;
    const bf16* vfrag = Vt + base + (size_t)lane * 8;
    const bf16* wrow = wp + b * SEQ + hi * 8;

    float m = -3e38f;
    f32x16 o0 = {}, o1 = {}, la = {};

    bf16x8 kfA[4], kfB[4];
    {
        const size_t tb0 = (size_t)(kp >> 1) * 4096;
        const int kh0 = kp & 1;
#pragma unroll
        for (int dc = 0; dc < 4; dc++)
            kfA[dc] = *(const bf16x8*)(kfrag + tb0 + (kh0 * 4 + dc) * 512);
    }

#define ITER(T, KFC, KFN)                                                                 \
    {                                                                                     \
        const int kt = 2 * (T) + kp;                                                      \
        const size_t tb = (size_t)(kt >> 1) * 4096;                                       \
        const int khalf = kt & 1;                                                         \
        f32x16 s = {};                                                                    \
        _Pragma("unroll")                                                                 \
        for (int dc = 0; dc < 4; dc++)                                                    \
            s = __builtin_amdgcn_mfma_f32_32x32x16_bf16(KFC[dc], qf[dc], s, 0, 0, 0);     \
        { /* prefetch next-iteration K (benign over-read on final iter) */                \
            const int kn = kt + 2;                                                        \
            const size_t tbn = (size_t)(kn >> 1) * 4096;                                  \
            const int khn = kn & 1;                                                       \
            _Pragma("unroll")                                                             \
            for (int dc = 0; dc < 4; dc++)                                                \
                KFN[dc] = *(const bf16x8*)(kfrag + tbn + (khn * 4 + dc) * 512);           \
        }                                                                                 \
        bf16x8 vf[4];                                                                     \
        vf[0] = *(const bf16x8*)(vfrag + tb + (khalf * 2 + 0) * 512);                     \
        vf[1] = *(const bf16x8*)(vfrag + tb + (khalf * 2 + 1) * 512);                     \
        vf[2] = *(const bf16x8*)(vfrag + tb + (4 + khalf * 2 + 0) * 512);                 \
        vf[3] = *(const bf16x8*)(vfrag + tb + (4 + khalf * 2 + 1) * 512);                 \
        bf16x8 wf0 = *(const bf16x8*)(wrow + kt * 32);                                    \
        bf16x8 wf1 = *(const bf16x8*)(wrow + kt * 32 + 16);                               \
        smax16(s, m, o0, o1, la);                                                         \
        bf16x8 pa[2];                                                                     \
        pconv16(s, pa);                                                                   \
        la = __builtin_amdgcn_mfma_f32_32x32x16_bf16(wf0, pa[0], la, 0, 0, 0);            \
        la = __builtin_amdgcn_mfma_f32_32x32x16_bf16(wf1, pa[1], la, 0, 0, 0);            \
        o0 = __builtin_amdgcn_mfma_f32_32x32x16_bf16(vf[0], pa[0], o0, 0, 0, 0);          \
        o0 = __builtin_amdgcn_mfma_f32_32x32x16_bf16(vf[1], pa[1], o0, 0, 0, 0);          \
        o1 = __builtin_amdgcn_mfma_f32_32x32x16_bf16(vf[2], pa[0], o1, 0, 0, 0);          \
        o1 = __builtin_amdgcn_mfma_f32_32x32x16_bf16(vf[3], pa[1], o1, 0, 0, 0);          \
    }

    for (int t = 0; t < SEQ / 64; t += 2) {
        ITER(t, kfA, kfB);
        ITER(t + 1, kfB, kfA);
    }
#undef ITER

    float l = la[0];

    // ---- split-K merge: kp1 parks state, kp0 combines ----
    if (kp == 1) {
#pragma unroll
        for (int i = 0; i < 16; i++) {
            Sm[qg][i * 64 + lane]        = o0[i];
            Sm[qg][(16 + i) * 64 + lane] = o1[i];
        }
        Sml[qg][lane] = m; Sml[qg][64 + lane] = l;
    }
    __syncthreads();
    if (kp == 1) return;

    {
        float mB = Sml[qg][lane], lB = Sml[qg][64 + lane];
        float mm = fmaxf(m, mB);
        float a = __builtin_amdgcn_exp2f(m - mm);
        float bb_ = __builtin_amdgcn_exp2f(mB - mm);
        l = l * a + lB * bb_;
#pragma unroll
        for (int i = 0; i < 16; i++) {
            o0[i] = o0[i] * a + Sm[qg][i * 64 + lane] * bb_;
            o1[i] = o1[i] * a + Sm[qg][(16 + i) * 64 + lane] * bb_;
        }
    }

    // ---- epilogue: O/l -> Ep (swizzled) -> ctx FRAG-PACKED for oproj ----
    float inv = 1.f / l;
    bf16* ep = Ep[qg];
    const int sw = (lq & 7) << 4;
#pragma unroll
    for (int g = 0; g < 4; g++) {
        bf16x4 p0, p1;
#pragma unroll
        for (int j = 0; j < 4; j++) {
            p0[j] = (bf16)(o0[g * 4 + j] * inv);
            p1[j] = (bf16)(o1[g * 4 + j] * inv);
        }
        int colb = g * 16 + hi * 8;
        *(bf16x4*)((char*)ep + lq * 128 + (colb ^ sw)) = p0;
        *(bf16x4*)((char*)ep + lq * 128 + ((64 + colb) ^ sw)) = p1;
    }
    const int c = lane & 15, gg = lane >> 4;
#pragma unroll
    for (int mt = 0; mt < 2; mt++) {
#pragma unroll
        for (int s2 = 0; s2 < 2; s2++) {
            int row = mt * 16 + c;
            int colb = (s2 * 64 + gg * 16) ^ ((row & 7) << 4);
            bf16x8 val = *(const bf16x8*)((const char*)ep + row * 128 + colb);
            size_t mtg = (size_t)((b * SEQ + qw) >> 4) + mt;
            *(bf16x8*)(ctxp + ((mtg * 24 + h * 2 + s2) * 64 + lane) * 8) = val;
        }
    }
}

// ============ fused output projection + bias + residual + LayerNorm ============
// grid 256 blocks (1/CU) x 512 threads (8 waves). Block computes rows [r0,r0+32) x all 768 cols;
// y stays in registers (no y round-trip through HBM). Wave covers 96 cols (2 mtiles x 6 ntiles).
__global__ __launch_bounds__(512, 2) void oproj_ln(
    const bf16* __restrict__ Cp, const bf16* __restrict__ Wo, const float* __restrict__ bo,
    const float* __restrict__ hidden, const float* __restrict__ gam,
    const float* __restrict__ bet, float* __restrict__ out)
{
    __shared__ float Par[8][32][2];

    const int lane = threadIdx.x & 63;
    const int wid = threadIdx.x >> 6;          // 0..7
    const int g = lane >> 4, c = lane & 15;
    const int r0 = blockIdx.x * 32;
    const int n0 = wid * 96;

    f32x4 acc[2][6] = {};
    const bf16* Ap = Cp + ((size_t)(r0 >> 4) * 24) * 512 + (size_t)lane * 8;
    const bf16* Bp = Wo + ((size_t)(n0 >> 4) * 24) * 512 + (size_t)lane * 8;

    bf16x8 a0[2], b0[6];
#pragma unroll
    for (int i = 0; i < 2; i++) a0[i] = *(const bf16x8*)(Ap + ((size_t)i * 24) * 512);
#pragma unroll
    for (int i = 0; i < 6; i++) b0[i] = *(const bf16x8*)(Bp + ((size_t)i * 24) * 512);

    for (int ks = 0; ks < 24; ks += 2) {
        bf16x8 a1[2], b1[6];
#pragma unroll
        for (int i = 0; i < 2; i++) a1[i] = *(const bf16x8*)(Ap + ((size_t)i * 24 + ks + 1) * 512);
#pragma unroll
        for (int i = 0; i < 6; i++) b1[i] = *(const bf16x8*)(Bp + ((size_t)i * 24 + ks + 1) * 512);
#pragma unroll
        for (int mi = 0; mi < 2; mi++)
#pragma unroll
            for (int ni = 0; ni < 6; ni++)
                acc[mi][ni] = __builtin_amdgcn_mfma_f32_16x16x32_bf16(a0[mi], b0[ni], acc[mi][ni], 0, 0, 0);
        int kn = (ks + 2 < 24) ? ks + 2 : 0;
#pragma unroll
        for (int i = 0; i < 2; i++) a0[i] = *(const bf16x8*)(Ap + ((size_t)i * 24 + kn) * 512);
#pragma unroll
        for (int i = 0; i < 6; i++) b0[i] = *(const bf16x8*)(Bp + ((size_t)i * 24 + kn) * 512);
#pragma unroll
        for (int mi = 0; mi < 2; mi++)
#pragma unroll
            for (int ni = 0; ni < 6; ni++)
                acc[mi][ni] = __builtin_amdgcn_mfma_f32_16x16x32_bf16(a1[mi], b1[ni], acc[mi][ni], 0, 0, 0);
    }

    // y = acc + bias + hidden (kept in registers)
    float bv[6];
#pragma unroll
    for (int ni = 0; ni < 6; ni++) bv[ni] = bo[n0 + ni * 16 + c];

#pragma unroll
    for (int mi = 0; mi < 2; mi++)
#pragma unroll
        for (int ni = 0; ni < 6; ni++)
#pragma unroll
            for (int j = 0; j < 4; j++) {
                int row = r0 + mi * 16 + g * 4 + j;
                int col = n0 + ni * 16 + c;
                acc[mi][ni][j] += bv[ni] + hidden[(size_t)row * HID + col];
            }

    // per-row partial sum/sumsq over this wave's 96 cols
#pragma unroll
    for (int mi = 0; mi < 2; mi++) {
#pragma unroll
        for (int j = 0; j < 4; j++) {
            float s = 0.f, q = 0.f;
#pragma unroll
            for (int ni = 0; ni < 6; ni++) {
                float v = acc[mi][ni][j];
                s += v; q += v * v;
            }
#pragma unroll
            for (int msk = 1; msk < 16; msk <<= 1) {
                s += __shfl_xor(s, msk);
                q += __shfl_xor(q, msk);
            }
            if (c == 0) {
                int rloc = mi * 16 + g * 4 + j;
                Par[wid][rloc][0] = s;
                Par[wid][rloc][1] = q;
            }
        }
    }
    __syncthreads();

    // finalize: mean/rstd per row, normalize, write
#pragma unroll
    for (int mi = 0; mi < 2; mi++) {
#pragma unroll
        for (int j = 0; j < 4; j++) {
            int rloc = mi * 16 + g * 4 + j;
            float S = 0.f, Q = 0.f;
#pragma unroll
            for (int w = 0; w < 8; w++) { S += Par[w][rloc][0]; Q += Par[w][rloc][1]; }
            float mean = S * (1.f / 768.f);
            float var = Q * (1.f / 768.f) - mean * mean;
            float rstd = rsqrtf(var + 1e-12f);
            int row = r0 + rloc;
#pragma unroll
            for (int ni = 0; ni < 6; ni++) {
                int col = n0 + ni * 16 + c;
                out[(size_t)row * HID + col] =
                    (acc[mi][ni][j] - mean) * rstd * gam[col] + bet[col];
            }
        }
    }
}

extern "C" void kernel_launch(void* const* d_in, const int* in_sizes, int n_in,
                              void* d_out, int out_size, void* d_ws, size_t ws_size,
                              hipStream_t stream) {
    const float* hidden = (const float*)d_in[0];
    const float* mask   = (const float*)d_in[1];
    const float* q_w = (const float*)d_in[2];
    const float* q_b = (const float*)d_in[3];
    const float* k_w = (const float*)d_in[4];
    const float* k_b = (const float*)d_in[5];
    const float* v_w = (const float*)d_in[6];
    const float* v_b = (const float*)d_in[7];
    const float* o_w = (const float*)d_in[8];
    const float* o_b = (const float*)d_in[9];
    const float* ln_g = (const float*)d_in[10];
    const float* ln_b = (const float*)d_in[11];
    float* out = (float*)d_out;

    const size_t SZ_X = (size_t)MTOT * HID;
    const size_t SZ_W = (size_t)HID * HID;

    char* ws = (char*)d_ws;
    size_t XB_OFF = 0;
    size_t W_OFF  = XB_OFF + SZ_X * 2;
    size_t QH_OFF = W_OFF + 4 * SZ_W * 2;
    size_t KH_OFF = QH_OFF + SZ_X * 2;
    size_t VT_OFF = KH_OFF + SZ_X * 2;
    size_t WE_OFF = VT_OFF + SZ_X * 2;           // wexp f32 (32KB)
    size_t WP_OFF = WE_OFF + (size_t)MTOT * 4;   // wp bf16 (16KB)

    bf16* Xp  = (bf16*)(ws + XB_OFF);
    bf16* Wqp = (bf16*)(ws + W_OFF);
    bf16* Wkp = Wqp + SZ_W;
    bf16* Wvp = Wkp + SZ_W;
    bf16* Wop = Wvp + SZ_W;
    bf16* Qh  = (bf16*)(ws + QH_OFF);
    bf16* Kh  = (bf16*)(ws + KH_OFF);
    bf16* Vt  = (bf16*)(ws + VT_OFF);
    float* wexp = (float*)(ws + WE_OFF);
    bf16* wp  = (bf16*)(ws + WP_OFF);
    bf16* ctxp = (bf16*)(ws + XB_OFF);   // alias: Xp dead after qkv_gemm

    pack_aw<<<dim3(512 + 4 * 48), 64, 0, stream>>>(hidden, q_w, k_w, v_w, o_w,
                                                   Xp, Wqp, Wkp, Wvp, Wop);
    prep_mask<<<dim3(MTOT / 256), 256, 0, stream>>>(mask, wexp, wp);

    qkv_gemm<<<dim3(HID / 128, MTOT / 128, 3), 256, 0, stream>>>(
        Xp, Wqp, Wkp, Wvp, q_b, k_b, v_b, wexp, Qh, Kh, Vt);

    // R11 config (best measured): 4-wave blocks, K-only ping-pong
    attn_kernel<<<dim3(NB * NHEAD, SEQ / 64), 256, 0, stream>>>(Qh, Kh, Vt, wp, ctxp);

    // fused oproj + bias + residual + LayerNorm (y never hits HBM)
    oproj_ln<<<dim3(MTOT / 32), 512, 0, stream>>>(ctxp, Wop, o_b, hidden, ln_g, ln_b, out);
}